// Round 5
// baseline (75.189 us; speedup 1.0000x reference)
//
#include <hip/hip_runtime.h>

// DSSIM = 1 - mean(SSIM), 11x11 gaussian (sigma=1.5), zero-pad, fp32.
// R3 structure (1 px/thread, stride-1 b32 LDS reads, zero bank conflicts)
// + T14 async staging: issue chunk c+1 global loads into regs before
// computing chunk c; transform+write to LDS after the compute barrier.

#define IMG_W   512
#define IMG_H   512
#define NPLANES 48

#define TW 256                 // tile width = blockDim.x (1 column/thread)
#define TH 32                  // output rows per block
#define ROWSV (TH + 10)        // 42 h-rows processed
#define LW 272                 // LDS row width: TW + 16 (float4-aligned halo)
#define NCHUNK 4               // ceil(42/11)
#define GX (IMG_W / TW)        // 2
#define GY (IMG_H / TH)        // 16
#define NBLK (GX * GY * NPLANES)   // 1536
#define NSLOT 748              // 11 rows * 68 float4 slots
#define NSTG 3                 // ceil(748/256) staging iters per thread

__global__ __launch_bounds__(256, 4)
void dssim_main(const float* __restrict__ xin, const float* __restrict__ yin,
                float* __restrict__ partial) {
    __shared__ float lsU[11][LW];      // u = x+y   11.9 KB
    __shared__ float lsW[11][LW];      // w = x-y   11.9 KB
    __shared__ float wpart[4];

    const int t   = threadIdx.x;
    const int tx0 = blockIdx.x * TW;
    const int ty0 = blockIdx.y * TH;
    const size_t pbase = (size_t)blockIdx.z * (IMG_W * IMG_H);
    const int base4 = (tx0 >> 2) - 2;  // first staged float4 column index
    const float* __restrict__ xp = xin + pbase;
    const float* __restrict__ yp = yin + pbase;

    float g[11];
    {
        float s = 0.f;
#pragma unroll
        for (int i = 0; i < 11; ++i) {
            float d = (float)(i - 5);
            g[i] = expf(-(d * d) * (1.0f / 4.5f));
            s += g[i];
        }
        float inv = 1.0f / s;
#pragma unroll
        for (int i = 0; i < 11; ++i) g[i] *= inv;
    }

    const float C1 = 0.0001f, C2 = 0.0009f;

    // async staging registers (statically indexed)
    float4 xr0, xr1, xr2, yr0, yr1, yr2;

    // issue global loads for chunk c (rows 11c .. 11c+10)
#define PH_LOAD(cc)                                                         \
    {                                                                       \
        const int c0_ = (cc) * 11;                                          \
        _Pragma("unroll")                                                   \
        for (int it = 0; it < NSTG; ++it) {                                 \
            const int idx = t + (it << 8);                                  \
            float4 xv = make_float4(0.f, 0.f, 0.f, 0.f);                    \
            float4 yv = make_float4(0.f, 0.f, 0.f, 0.f);                    \
            if (idx < NSLOT) {                                              \
                const int j_  = idx / 68;                                   \
                const int c4_ = idx - j_ * 68;                              \
                const int i_  = c0_ + j_;                                   \
                const int gr_ = ty0 - 5 + i_;                               \
                const int gc4_ = base4 + c4_;                               \
                if (i_ < ROWSV && gr_ >= 0 && gr_ < IMG_H &&                \
                    gc4_ >= 0 && gc4_ < (IMG_W / 4)) {                      \
                    const size_t o_ = (size_t)gr_ * IMG_W + (gc4_ << 2);    \
                    xv = *(const float4*)(xp + o_);                         \
                    yv = *(const float4*)(yp + o_);                         \
                }                                                           \
            }                                                               \
            if (it == 0) { xr0 = xv; yr0 = yv; }                            \
            else if (it == 1) { xr1 = xv; yr1 = yv; }                       \
            else { xr2 = xv; yr2 = yv; }                                    \
        }                                                                   \
    }

    // transform u=x+y, w=x-y and write staged regs to LDS
#define PH_WRITE()                                                          \
    {                                                                       \
        _Pragma("unroll")                                                   \
        for (int it = 0; it < NSTG; ++it) {                                 \
            const int idx = t + (it << 8);                                  \
            if (idx < NSLOT) {                                              \
                const int j_  = idx / 68;                                   \
                const int c4_ = idx - j_ * 68;                              \
                const float4 xv = (it == 0) ? xr0 : (it == 1) ? xr1 : xr2;  \
                const float4 yv = (it == 0) ? yr0 : (it == 1) ? yr1 : yr2;  \
                float4 u_, w_;                                              \
                u_.x = xv.x + yv.x; u_.y = xv.y + yv.y;                     \
                u_.z = xv.z + yv.z; u_.w = xv.w + yv.w;                     \
                w_.x = xv.x - yv.x; w_.y = xv.y - yv.y;                     \
                w_.z = xv.z - yv.z; w_.w = xv.w - yv.w;                     \
                *(float4*)&lsU[j_][c4_ << 2] = u_;                          \
                *(float4*)&lsW[j_][c4_ << 2] = w_;                          \
            }                                                               \
        }                                                                   \
    }

    // vertical rings of h-blurred {u, w, u^2, w^2}, slot = row % 11
    float rU[11], rW[11], rP[11], rQ[11];
    float lsum = 0.f;

    // prologue: stage chunk 0
    PH_LOAD(0);
    PH_WRITE();
    __syncthreads();

    for (int c = 0; c < NCHUNK; ++c) {
        const int c0 = c * 11;

        if (c + 1 < NCHUNK) PH_LOAD(c + 1);   // async: hide under compute

        // ---- h-blur each row into rings; v-blur + ssim once warm ----
#pragma unroll
        for (int j = 0; j < 11; ++j) {
            const int i = c0 + j;                 // i % 11 == j
            if (i < ROWSV) {
                float au = 0.f, aw = 0.f, pu = 0.f, pw = 0.f;
#pragma unroll
                for (int k = 0; k < 11; ++k) {
                    const float vu = lsU[j][t + 3 + k];
                    const float vw = lsW[j][t + 3 + k];
                    const float gk = g[k];
                    au = fmaf(gk, vu, au);
                    aw = fmaf(gk, vw, aw);
                    pu = fmaf(gk * vu, vu, pu);
                    pw = fmaf(gk * vw, vw, pw);
                }
                rU[j] = au; rW[j] = aw; rP[j] = pu; rQ[j] = pw;

                if (i >= 10) {                    // output row (i-10)
                    float U = 0.f, W = 0.f, P = 0.f, Q = 0.f;
#pragma unroll
                    for (int k = 0; k < 11; ++k) {
                        const int s = (j + 1 + k) % 11;   // oldest-first
                        const float gk = g[k];
                        U = fmaf(gk, rU[s], U);
                        W = fmaf(gk, rW[s], W);
                        P = fmaf(gk, rP[s], P);
                        Q = fmaf(gk, rQ[s], Q);
                    }
                    // U=mu1+mu2, W=mu1-mu2, (P+Q)/2=Exx+Eyy, (P-Q)/4=Exy
                    const float U2 = U * U;
                    const float W2 = W * W;
                    const float A  = 0.5f * (U2 + W2);    // m11+m22
                    const float B  = 0.5f * (U2 - W2);    // 2*m12
                    const float den2 = fmaf(0.5f, P + Q, -A) + C2;
                    const float num2 = fmaf(0.5f, P - Q, -B) + C2;
                    lsum += (B + C1) * num2 *
                            __builtin_amdgcn_rcpf((A + C1) * den2);
                }
            }
        }

        __syncthreads();                          // all waves done reading
        if (c + 1 < NCHUNK) PH_WRITE();           // vmcnt drained here (cheap)
        __syncthreads();                          // writes visible
    }

    // ---- block reduction ----
#pragma unroll
    for (int off = 32; off >= 1; off >>= 1)
        lsum += __shfl_down(lsum, off, 64);
    if ((t & 63) == 0) wpart[t >> 6] = lsum;
    __syncthreads();
    if (t == 0) {
        partial[((size_t)blockIdx.z * GY + blockIdx.y) * GX + blockIdx.x] =
            wpart[0] + wpart[1] + wpart[2] + wpart[3];
    }
}

__global__ __launch_bounds__(256)
void dssim_final(const float* __restrict__ partial, float* __restrict__ out) {
    __shared__ double wsum[4];
    double s = 0.0;
    for (int i = threadIdx.x; i < NBLK; i += 256) s += (double)partial[i];
#pragma unroll
    for (int off = 32; off >= 1; off >>= 1)
        s += __shfl_down(s, off, 64);
    if ((threadIdx.x & 63) == 0) wsum[threadIdx.x >> 6] = s;
    __syncthreads();
    if (threadIdx.x == 0) {
        const double tot = wsum[0] + wsum[1] + wsum[2] + wsum[3];
        out[0] = (float)(1.0 - tot / 12582912.0);
    }
}

extern "C" void kernel_launch(void* const* d_in, const int* in_sizes, int n_in,
                              void* d_out, int out_size, void* d_ws, size_t ws_size,
                              hipStream_t stream) {
    const float* x = (const float*)d_in[0];
    const float* y = (const float*)d_in[1];
    float* out = (float*)d_out;
    float* partial = (float*)d_ws;   // NBLK*4 = 6 KiB

    dim3 grid(GX, GY, NPLANES);      // 2 x 16 x 48 = 1536 blocks
    dim3 block(256);
    dssim_main<<<grid, block, 0, stream>>>(x, y, partial);
    dssim_final<<<1, block, 0, stream>>>(partial, out);
}

// Round 6
// 55.141 us; speedup vs baseline: 1.3636x; 1.3636x over previous
//
#include <hip/hip_runtime.h>

// DSSIM = 1 - mean(SSIM), 11x11 gaussian (sigma=1.5), zero-pad, fp32.
// R3 skeleton (sync staging, 1 px/thread, TH=32, 1536 blocks) with:
//  - LDS interleaved (u,w) float2 rows -> h-blur reads ds_read_b64
//  - packed f32 math (f32x2 + elementwise_fma -> v_pk_fma_f32)
// Channels: u=x+y, w=x-y; P=conv(u^2), Q=conv(w^2);
// mu1+mu2=U, mu1-mu2=W, s1+s2=(P+Q)/2-..., 2*s12=(P-Q)/2-...

typedef float f32x2 __attribute__((ext_vector_type(2)));

#define IMG_W   512
#define IMG_H   512
#define NPLANES 48

#define TW 256                 // tile width = blockDim.x (1 column/thread)
#define TH 32                  // output rows per block
#define ROWSV (TH + 10)        // 42 h-rows processed
#define LW 272                 // f32x2 slots per row (16 halo + 256)
#define NCHUNK 4               // ceil(42/11)
#define GX (IMG_W / TW)        // 2
#define GY (IMG_H / TH)        // 16
#define NBLK (GX * GY * NPLANES)   // 1536

__global__ __launch_bounds__(256, 4)
void dssim_main(const float* __restrict__ xin, const float* __restrict__ yin,
                float* __restrict__ partial) {
    __shared__ f32x2 ls[11][LW];       // (u,w) interleaved  23.9 KB
    __shared__ float wpart[4];

    const int t   = threadIdx.x;
    const int tx0 = blockIdx.x * TW;
    const int ty0 = blockIdx.y * TH;
    const size_t pbase = (size_t)blockIdx.z * (IMG_W * IMG_H);
    const int base4 = (tx0 >> 2) - 2;  // first staged float4 column index
    const float* __restrict__ xp = xin + pbase;
    const float* __restrict__ yp = yin + pbase;

    float g[11];
    {
        float s = 0.f;
#pragma unroll
        for (int i = 0; i < 11; ++i) {
            float d = (float)(i - 5);
            g[i] = expf(-(d * d) * (1.0f / 4.5f));
            s += g[i];
        }
        float inv = 1.0f / s;
#pragma unroll
        for (int i = 0; i < 11; ++i) g[i] *= inv;
    }

    const float C1 = 0.0001f, C2 = 0.0009f;

    // vertical rings of h-blurred (U,W) and (P,Q) pairs, slot = row % 11
    f32x2 rA[11], rS[11];
    float lsum = 0.f;

    for (int c = 0; c < NCHUNK; ++c) {
        const int c0 = c * 11;

        // ---- stage 11 rows: (u,w) interleaved, float4 writes ----
        __syncthreads();
        for (int idx = t; idx < 11 * 68; idx += 256) {
            const int j   = idx / 68;               // row slot 0..10
            const int c4  = idx - j * 68;           // float4 col in tile
            const int i   = c0 + j;
            const int gr  = ty0 - 5 + i;
            const int gc4 = base4 + c4;
            float4 xv = make_float4(0.f, 0.f, 0.f, 0.f);
            float4 yv = make_float4(0.f, 0.f, 0.f, 0.f);
            if (i < ROWSV && gr >= 0 && gr < IMG_H && gc4 >= 0 && gc4 < (IMG_W / 4)) {
                const size_t o = (size_t)gr * IMG_W + (gc4 << 2);
                xv = *(const float4*)(xp + o);
                yv = *(const float4*)(yp + o);
            }
            float4 a, b;                            // (u0,w0,u1,w1),(u2,w2,u3,w3)
            a.x = xv.x + yv.x; a.y = xv.x - yv.x;
            a.z = xv.y + yv.y; a.w = xv.y - yv.y;
            b.x = xv.z + yv.z; b.y = xv.z - yv.z;
            b.z = xv.w + yv.w; b.w = xv.w - yv.w;
            *(float4*)&ls[j][(c4 << 2)]     = a;
            *(float4*)&ls[j][(c4 << 2) + 2] = b;
        }
        __syncthreads();

        // ---- h-blur each row into rings; v-blur + ssim once warm ----
#pragma unroll
        for (int j = 0; j < 11; ++j) {
            const int i = c0 + j;                 // i % 11 == j
            if (i < ROWSV) {
                f32x2 ha = {0.f, 0.f};            // (au, aw)
                f32x2 hp = {0.f, 0.f};            // (pu, pw)
#pragma unroll
                for (int k = 0; k < 11; ++k) {
                    const f32x2 v = ls[j][t + 3 + k];
                    const f32x2 gk2 = {g[k], g[k]};
                    ha = __builtin_elementwise_fma(gk2, v, ha);
                    hp = __builtin_elementwise_fma(gk2 * v, v, hp);
                }
                rA[j] = ha; rS[j] = hp;

                if (i >= 10) {                    // output row (i-10)
                    f32x2 A2 = {0.f, 0.f};        // (U, W)
                    f32x2 S2 = {0.f, 0.f};        // (P, Q)
#pragma unroll
                    for (int k = 0; k < 11; ++k) {
                        const int s = (j + 1 + k) % 11;   // oldest-first
                        const f32x2 gk2 = {g[k], g[k]};
                        A2 = __builtin_elementwise_fma(gk2, rA[s], A2);
                        S2 = __builtin_elementwise_fma(gk2, rS[s], S2);
                    }
                    const float U = A2.x, W = A2.y, P = S2.x, Q = S2.y;
                    const float U2 = U * U;
                    const float W2 = W * W;
                    const float A  = 0.5f * (U2 + W2);    // m11+m22
                    const float B  = 0.5f * (U2 - W2);    // 2*m12
                    const float den2 = fmaf(0.5f, P + Q, -A) + C2;
                    const float num2 = fmaf(0.5f, P - Q, -B) + C2;
                    lsum += (B + C1) * num2 *
                            __builtin_amdgcn_rcpf((A + C1) * den2);
                }
            }
        }
    }

    // ---- block reduction ----
#pragma unroll
    for (int off = 32; off >= 1; off >>= 1)
        lsum += __shfl_down(lsum, off, 64);
    if ((t & 63) == 0) wpart[t >> 6] = lsum;
    __syncthreads();
    if (t == 0) {
        partial[((size_t)blockIdx.z * GY + blockIdx.y) * GX + blockIdx.x] =
            wpart[0] + wpart[1] + wpart[2] + wpart[3];
    }
}

__global__ __launch_bounds__(256)
void dssim_final(const float* __restrict__ partial, float* __restrict__ out) {
    __shared__ double wsum[4];
    double s = 0.0;
    for (int i = threadIdx.x; i < NBLK; i += 256) s += (double)partial[i];
#pragma unroll
    for (int off = 32; off >= 1; off >>= 1)
        s += __shfl_down(s, off, 64);
    if ((threadIdx.x & 63) == 0) wsum[threadIdx.x >> 6] = s;
    __syncthreads();
    if (threadIdx.x == 0) {
        const double tot = wsum[0] + wsum[1] + wsum[2] + wsum[3];
        out[0] = (float)(1.0 - tot / 12582912.0);
    }
}

extern "C" void kernel_launch(void* const* d_in, const int* in_sizes, int n_in,
                              void* d_out, int out_size, void* d_ws, size_t ws_size,
                              hipStream_t stream) {
    const float* x = (const float*)d_in[0];
    const float* y = (const float*)d_in[1];
    float* out = (float*)d_out;
    float* partial = (float*)d_ws;   // NBLK*4 = 6 KiB

    dim3 grid(GX, GY, NPLANES);      // 2 x 16 x 48 = 1536 blocks
    dim3 block(256);
    dssim_main<<<grid, block, 0, stream>>>(x, y, partial);
    dssim_final<<<1, block, 0, stream>>>(partial, out);
}